// Round 5
// baseline (980.418 us; speedup 1.0000x reference)
//
#include <hip/hip_runtime.h>
#include <hip/hip_bf16.h>

#define VOCAB 50000
#define DD 128
#define TT 512
#define BB 512
#define HH 100
#define NCLS 4
#define NT 25            // 16-wide permuted z-col tiles covering 4H=400 exactly
#define ROWS 4           // real batch rows per block
#define NBLK (BB/ROWS)   // 128 blocks
#define NTHREADS 512     // 8 waves

typedef short s16x8 __attribute__((ext_vector_type(8)));
typedef float f32x4 __attribute__((ext_vector_type(4)));

static __device__ __forceinline__ unsigned short f2b(float x) {
    __hip_bfloat16 h = __float2bfloat16(x);
    return __builtin_bit_cast(unsigned short, h);
}
static __device__ __forceinline__ float sigm(float x)  { return __fdividef(1.0f, 1.0f + __expf(-x)); }
static __device__ __forceinline__ float tanhx(float x) { return 1.0f - __fdividef(2.0f, 1.0f + __expf(2.0f * x)); }

// raw barrier: waits LDS ops only; global loads (vmcnt) stay in flight
#define BARRIER() asm volatile("s_waitcnt lgkmcnt(0)\n\ts_barrier" ::: "memory")

// ---------------- prep: cast embedding table f32 -> bf16 ----------------
__global__ void cast_emb_k(const float* __restrict__ emb, unsigned short* __restrict__ out, int n4) {
    int i = blockIdx.x * blockDim.x + threadIdx.x;
    if (i < n4) {
        float4 v = reinterpret_cast<const float4*>(emb)[i];
        ushort4 o = make_ushort4(f2b(v.x), f2b(v.y), f2b(v.z), f2b(v.w));
        reinterpret_cast<ushort4*>(out)[i] = o;
    }
}

// ---------------- prep: bake kernel & rec_kernel into per-lane MFMA fragments ----------------
// PERMUTED columns: dest col c' = j*4 + gate  <->  orig col = (c'&3)*100 + (c'>>2)
// frag(nt, ks), lane l, elem j <- M[k = ks*32 + (l>>4)*8 + j][orig_col(nt*16 + (l&15))]
// Used as the A-operand of the TRANSPOSED product: A[m=c'][k] = W^T[c'][k].
__global__ void build_frags_k(const float* __restrict__ kern, const float* __restrict__ rec,
                              unsigned short* __restrict__ ikf, unsigned short* __restrict__ recf) {
    int tid = blockIdx.x * blockDim.x + threadIdx.x;
    if (tid >= 2 * NT * 4 * 64) return;
    int tab  = tid / (NT * 4 * 64);
    int rem  = tid % (NT * 4 * 64);
    int lane = rem & 63;
    int fs   = rem >> 6;
    int ks   = fs & 3, nt = fs >> 2;
    int cp    = nt * 16 + (lane & 15);           // permuted col (= A row m)
    int oc    = (cp & 3) * 100 + (cp >> 2);      // original col
    int kbase = ks * 32 + (lane >> 4) * 8;
    unsigned short* dst = (tab ? recf : ikf) + rem * 8;
#pragma unroll
    for (int j = 0; j < 8; ++j) {
        int k = kbase + j;
        float v;
        if (tab == 0) v = kern[k * 400 + oc];
        else          v = (k < HH) ? rec[k * 400 + oc] : 0.0f;
        dst[j] = f2b(v);
    }
}

// ---------------- fused LSTM: transposed MFMA, in-register gates, 1 barrier/step ----------------
__global__ __launch_bounds__(NTHREADS, 2)
void lstm_fused3_k(const int* __restrict__ tokens,
                   const float* __restrict__ bias,
                   const float* __restrict__ dw,
                   const float* __restrict__ db,
                   const unsigned short* __restrict__ emb_bf,
                   const unsigned short* __restrict__ ikf_tab,
                   const unsigned short* __restrict__ recf_tab,
                   float* __restrict__ out)
{
    __shared__ __align__(16) unsigned short h_lds[2][16 * DD]; // bf16 h dbuf; rows r,r+4,r+8,r+12 replicate row r; k>=100 zero
    __shared__ float hf_lds[ROWS * HH];
    __shared__ float dw_lds[HH * NCLS];
    __shared__ int   tok_lds[ROWS][TT];

    const int tid = threadIdx.x, lane = tid & 63, w = tid >> 6;
    const int lo = lane & 15, hi = lane >> 4;
    const int b0 = blockIdx.x * ROWS;
    const int nt0 = (w * NT) >> 3;
    const int cnt = (((w + 1) * NT) >> 3) - nt0;   // 3 or 4 tiles per wave

    // weight A-fragments + bias quads live in registers/AGPRs the whole kernel
    s16x8 ikf[4][4], rcf[4][4];
    f32x4 bvq[4];
#pragma unroll
    for (int i = 0; i < 4; ++i) {
        if (i < cnt) {
#pragma unroll
            for (int r = 0; r < 4; ++r)
                bvq[i][r] = bias[r * 100 + (nt0 + i) * 4 + hi];   // bias[orig_col(c')], c'=(nt0+i)*16+hi*4+r
#pragma unroll
            for (int ks = 0; ks < 4; ++ks) {
                ikf[i][ks] = *reinterpret_cast<const s16x8*>(ikf_tab  + (((nt0 + i) * 4 + ks) * 64 + lane) * 8);
                rcf[i][ks] = *reinterpret_cast<const s16x8*>(recf_tab + (((nt0 + i) * 4 + ks) * 64 + lane) * 8);
            }
        } else {
            bvq[i] = (f32x4)0.f;
#pragma unroll
            for (int ks = 0; ks < 4; ++ks) { ikf[i][ks] = (s16x8)0; rcf[i][ks] = (s16x8)0; }
        }
    }
#pragma unroll
    for (int i = 0; i < 4; ++i) {
        asm volatile("" : "+v"(bvq[i]));
#pragma unroll
        for (int ks = 0; ks < 4; ++ks) {
            asm volatile("" : "+v"(ikf[i][ks]));
            asm volatile("" : "+v"(rcf[i][ks]));
        }
    }

    for (int idx = tid; idx < 16 * DD; idx += NTHREADS)   // zero both h buffers
        reinterpret_cast<unsigned int*>(&h_lds[0][0])[idx] = 0u;
    for (int idx = tid; idx < ROWS * TT; idx += NTHREADS)
        tok_lds[idx >> 9][idx & (TT - 1)] = tokens[(b0 + (idx >> 9)) * TT + (idx & (TT - 1))];
    if (tid < HH * NCLS) dw_lds[tid] = dw[tid];

    const int xrow = lo & 3;        // B-operand col n = lo; cols 4..15 duplicate rows 0..3 (pad, C cols unused)
    float cst[4] = {0.f, 0.f, 0.f, 0.f};

    int hof[4];
#pragma unroll
    for (int ks = 0; ks < 4; ++ks)
        hof[ks] = (lo * 256 + ks * 64 + hi * 16) ^ ((lo & 7) << 4);  // replicated rows -> old 2-way-free pattern

    // x prefetch: 2-deep alternating buffers
    s16x8 xfA[4], xfB[4];
    {
        int t0 = tokens[(b0 + xrow) * TT + 0];
        int t1 = tokens[(b0 + xrow) * TT + 1];
#pragma unroll
        for (int ks = 0; ks < 4; ++ks) {
            xfA[ks] = *reinterpret_cast<const s16x8*>(emb_bf + (long)t0 * DD + ks * 32 + hi * 8);
            xfB[ks] = *reinterpret_cast<const s16x8*>(emb_bf + (long)t1 * DD + ks * 32 + hi * 8);
        }
    }
    __syncthreads();

    auto step = [&](int t, s16x8 (&xf)[4],
                    const unsigned short* hrd, unsigned short* hwr) {
        // h^T B-fragments from swizzled LDS (issue first; latency overlaps x-MFMAs)
        s16x8 hB[4];
#pragma unroll
        for (int ks = 0; ks < 4; ++ks)
            hB[ks] = *reinterpret_cast<const s16x8*>(reinterpret_cast<const char*>(hrd) + hof[ks]);

        f32x4 acc[4];
#pragma unroll
        for (int i = 0; i < 4; ++i) acc[i] = bvq[i];

        // x-part: z^T += W_k^T x^T  (xf loaded 2 steps ago; runs while hB in flight)
#pragma unroll
        for (int ks = 0; ks < 4; ++ks)
#pragma unroll
            for (int i = 0; i < 4; ++i)
                if (i < cnt) acc[i] = __builtin_amdgcn_mfma_f32_16x16x32_bf16(ikf[i][ks], xf[ks], acc[i], 0, 0, 0);

        // issue x prefetch for t+2 into the just-freed buffer
        {
            int t2 = (t + 2 < TT) ? t + 2 : TT - 1;
            int tk = tok_lds[xrow][t2];
            const unsigned short* ep = emb_bf + (long)tk * DD;
#pragma unroll
            for (int ks = 0; ks < 4; ++ks)
                xf[ks] = *reinterpret_cast<const s16x8*>(ep + ks * 32 + hi * 8);
        }

        // h-part: z^T += U^T h^T
#pragma unroll
        for (int ks = 0; ks < 4; ++ks)
#pragma unroll
            for (int i = 0; i < 4; ++i)
                if (i < cnt) acc[i] = __builtin_amdgcn_mfma_f32_16x16x32_bf16(rcf[i][ks], hB[ks], acc[i], 0, 0, 0);

        // gates IN-REGISTER: acc[i][0..3] = (i,f,g,o) of (row=lo, j=(nt0+i)*4+hi)
        if (lo < ROWS) {
#pragma unroll
            for (int i = 0; i < 4; ++i) if (i < cnt) {
                float ig = sigm(acc[i][0]), fg = sigm(acc[i][1]);
                float gg = tanhx(acc[i][2]), og = sigm(acc[i][3]);
                cst[i] = fg * cst[i] + ig * gg;
                float hh = og * tanhx(cst[i]);
                unsigned short hb = f2b(hh);
                int j2 = ((nt0 + i) * 4 + hi) * 2;
#pragma unroll
                for (int rep = 0; rep < 4; ++rep) {
                    int row = lo + 4 * rep;
                    *reinterpret_cast<unsigned short*>(reinterpret_cast<char*>(hwr) +
                        ((row * 256 + j2) ^ ((row & 7) << 4))) = hb;
                }
                if (t == TT - 1) hf_lds[lo * HH + (j2 >> 1)] = hh;
            }
        }
        BARRIER();
    };

    for (int t = 0; t < TT; t += 2) {
        step(t,     xfA, h_lds[1], h_lds[0]);   // read h_{t-1} from buf1, write h_t to buf0
        step(t + 1, xfB, h_lds[0], h_lds[1]);   // read buf0, write buf1
    }

    // epilogue: logits + softmax for this block's 4 rows
    if (tid < ROWS * NCLS) {
        int r = tid >> 2, c = tid & 3;
        float s = db[c];
#pragma unroll 4
        for (int k = 0; k < HH; ++k)
            s += hf_lds[r * HH + k] * dw_lds[k * NCLS + c];
        float mx = s;
        mx = fmaxf(mx, __shfl_xor(mx, 1));
        mx = fmaxf(mx, __shfl_xor(mx, 2));
        float e = __expf(s - mx);
        float den = e;
        den += __shfl_xor(den, 1);
        den += __shfl_xor(den, 2);
        out[(b0 + r) * NCLS + c] = e / den;
    }
}

extern "C" void kernel_launch(void* const* d_in, const int* in_sizes, int n_in,
                              void* d_out, int out_size, void* d_ws, size_t ws_size,
                              hipStream_t stream) {
    const int*   tokens = (const int*)d_in[0];
    const float* emb    = (const float*)d_in[1];
    const float* kern   = (const float*)d_in[2];
    const float* rec    = (const float*)d_in[3];
    const float* bias   = (const float*)d_in[4];
    const float* dw     = (const float*)d_in[5];
    const float* db     = (const float*)d_in[6];
    float* out = (float*)d_out;

    // ws layout: emb_bf16 (12.8MB) | ikf (100KB) | recf (100KB)
    unsigned short* emb_bf = (unsigned short*)d_ws;
    unsigned short* ikf    = emb_bf + (size_t)VOCAB * DD;
    unsigned short* recf   = ikf + NT * 4 * 64 * 8;

    int n4 = VOCAB * DD / 4;
    cast_emb_k<<<(n4 + 255) / 256, 256, 0, stream>>>(emb, emb_bf, n4);
    build_frags_k<<<(2 * NT * 4 * 64 + 255) / 256, 256, 0, stream>>>(kern, rec, ikf, recf);
    lstm_fused3_k<<<NBLK, NTHREADS, 0, stream>>>(tokens, bias, dw, db, emb_bf, ikf, recf, out);
}